// Round 7
// baseline (943.512 us; speedup 1.0000x reference)
//
#include <hip/hip_runtime.h>

#define NN 100000
#define EE 1600000
#define FF 128
#define SS 256
#define CC 32
#define KG 384     // gates GEMM K = F + S
#define NCOL 1024  // gates GEMM N = 4 gates * S
#define RBMAX 6249 // last 16-row block index (NN/16 - 1)

typedef __attribute__((ext_vector_type(8))) short v8s;
typedef __attribute__((ext_vector_type(8))) unsigned short u8s;
typedef __attribute__((ext_vector_type(4))) float v4f;

// Fragment-major layout for MFMA operands: [blk16][ks][g][r][e] (bf16)
//   blk16 = row/16, ks = k/32, g = (k%32)/8, r = row%16, e = k%8
//   -> lane (g*16+r) reads its 8 elements at frag_base + lane*16B: 1KB contiguous per fragment.

__device__ __forceinline__ unsigned short f2bf(float f) {
  unsigned int u = __float_as_uint(f);
  u += 0x7FFF + ((u >> 16) & 1);  // RNE
  return (unsigned short)(u >> 16);
}
__device__ __forceinline__ float bf2f(unsigned short u) {
  return __uint_as_float(((unsigned int)u) << 16);
}
__device__ __forceinline__ float sigmoidf_(float x) { return 1.0f / (1.0f + __expf(-x)); }
__device__ __forceinline__ float tanhf_(float x) {
  float ax = fabsf(x);
  float e = __expf(2.0f * ax);
  float t = 1.0f - 2.0f / (e + 1.0f);
  return copysignf(t, x);
}

// ---------------- degree / norm + edge histogram ----------------
__global__ __launch_bounds__(256) void k_deg_init(float* deg, int* cnt) {
  int i = blockIdx.x * 256 + threadIdx.x;
  if (i < NN) { deg[i] = 1.0f; cnt[i] = 0; }
}
__global__ __launch_bounds__(256) void k_deg_acc(const int* __restrict__ dst,
                                                 const float* __restrict__ w,
                                                 float* __restrict__ deg,
                                                 int* __restrict__ cnt) {
  int e = blockIdx.x * 256 + threadIdx.x;
  if (e < EE) {
    int d = dst[e];
    unsafeAtomicAdd(&deg[d], w[e]);
    atomicAdd(&cnt[d], 1);
  }
}

// ---------------- CSR build: scan (fused dinv) + fill ----------------
__global__ __launch_bounds__(256) void k_scan1(const int* __restrict__ cnt, int* __restrict__ loc,
                                               int* __restrict__ blkSum, float* __restrict__ deg) {
  __shared__ int s[256];
  int i = blockIdx.x * 256 + threadIdx.x;
  if (i < NN) { float d = deg[i]; deg[i] = d > 0.f ? rsqrtf(d) : 0.f; }  // fused dinv
  int v = (i < NN) ? cnt[i] : 0;
  s[threadIdx.x] = v;
  __syncthreads();
#pragma unroll
  for (int d = 1; d < 256; d <<= 1) {
    int t = (threadIdx.x >= d) ? s[threadIdx.x - d] : 0;
    __syncthreads();
    s[threadIdx.x] += t;
    __syncthreads();
  }
  if (i < NN) loc[i] = s[threadIdx.x] - v;  // exclusive
  if (threadIdx.x == 255) blkSum[blockIdx.x] = s[255];
}
__global__ __launch_bounds__(512) void k_scan2(int* __restrict__ blkSum, int* __restrict__ blkOff, int nb) {
  __shared__ int s[512];
  int v = (threadIdx.x < nb) ? blkSum[threadIdx.x] : 0;
  s[threadIdx.x] = v;
  __syncthreads();
#pragma unroll
  for (int d = 1; d < 512; d <<= 1) {
    int t = (threadIdx.x >= d) ? s[threadIdx.x - d] : 0;
    __syncthreads();
    s[threadIdx.x] += t;
    __syncthreads();
  }
  if (threadIdx.x < nb) blkOff[threadIdx.x] = s[threadIdx.x] - v;  // exclusive
}
__global__ __launch_bounds__(256) void k_scan3(const int* __restrict__ loc, const int* __restrict__ blkOff,
                                               int* __restrict__ rowptr, int* __restrict__ cursor) {
  int i = blockIdx.x * 256 + threadIdx.x;
  if (i < NN) {
    int v = loc[i] + blkOff[blockIdx.x];
    rowptr[i] = v;
    cursor[i] = v;
  }
}
__global__ __launch_bounds__(256) void k_fill(const int* __restrict__ src, const int* __restrict__ dst,
                                              const float* __restrict__ w, const float* __restrict__ dinv,
                                              int* __restrict__ cursor, int2* __restrict__ epack) {
  int e = blockIdx.x * 256 + threadIdx.x;
  if (e >= EE) return;
  int s = src[e], d = dst[e];
  int pos = atomicAdd(&cursor[d], 1);
  float coef = dinv[s] * w[e] * dinv[d];
  int2 m; m.x = s; m.y = __float_as_int(coef);
  epack[pos] = m;
}

// ---------------- packs ----------------
__global__ __launch_bounds__(256) void k_pack_w1t(const float* __restrict__ W1, unsigned short* __restrict__ W1T) {
  int i = blockIdx.x * 256 + threadIdx.x;  // 128*128
  if (i < FF * FF) {
    int col = i >> 7, k = i & 127;
    W1T[i] = f2bf(W1[k * FF + col]);
  }
}
// B^T in fragment-major layout: Bf[cb][ks][g][r][e], col = (s&15)+16*gate+64*(s>>4)
__global__ __launch_bounds__(256) void k_pack_bfrag(const float* __restrict__ Wi, const float* __restrict__ Wf,
                                                    const float* __restrict__ Wc, const float* __restrict__ Wo,
                                                    const float* __restrict__ Ti, const float* __restrict__ Tf,
                                                    const float* __restrict__ Tc, const float* __restrict__ To,
                                                    unsigned short* __restrict__ Bf) {
  int i = blockIdx.x * 256 + threadIdx.x;  // 1024*384
  if (i >= NCOL * KG) return;
  int col = i / KG, k = i - col * KG;
  int th = col >> 6, rem = col & 63, g8 = rem >> 4, slo = rem & 15;
  int s = th * 16 + slo;
  const float* Wp = (g8 == 0) ? Wi : (g8 == 1) ? Wf : (g8 == 2) ? Wc : Wo;
  const float* Tp = (g8 == 0) ? Ti : (g8 == 1) ? Tf : (g8 == 2) ? Tc : To;
  float v = (k < FF) ? Wp[(size_t)k * SS + s] : Tp[(size_t)(k - FF) * SS + s];
  int cb = col >> 4, lc = col & 15, ks = k >> 5, g = (k & 31) >> 3, e = k & 7;
  Bf[(((size_t)cb * 12 + ks) * 512) + g * 128 + lc * 8 + e] = f2bf(v);
}
__global__ __launch_bounds__(256) void k_pack_bias(const float* bci, const float* bcf, const float* bcc, const float* bco,
                                                   const float* bi, const float* bf, const float* bc_, const float* bo,
                                                   float* biasP) {
  int col = blockIdx.x * 256 + threadIdx.x;
  if (col >= NCOL) return;
  int th = col >> 6, rem = col & 63, g = rem >> 4, slo = rem & 15;
  int s = th * 16 + slo;
  const float* P = (g == 0) ? bci : (g == 1) ? bcf : (g == 2) ? bcc : bco;
  const float* Q = (g == 0) ? bi : (g == 1) ? bf : (g == 2) ? bc_ : bo;
  biasP[col] = P[s] + Q[s];
}
// Wl^T in fragment-major: Wlf[cb(2)][ks(8)][g][r][e]
__global__ __launch_bounds__(256) void k_pack_wlf(const float* __restrict__ Wl, unsigned short* __restrict__ Wlf) {
  int i = blockIdx.x * 256 + threadIdx.x;  // 32*256
  if (i >= CC * SS) return;
  int c = i >> 8, k = i & 255;
  float v = Wl[(size_t)k * CC + c];
  int cb = c >> 4, lc = c & 15, ks = k >> 5, g = (k & 31) >> 3, e = k & 7;
  Wlf[(((size_t)cb * 8 + ks) * 512) + g * 128 + lc * 8 + e] = f2bf(v);
}

// ---------------- GEMM1: xw = f2bf(x) @ W1, fused fp32->bf16 pack ----------------
__global__ __launch_bounds__(256) void k_gemm1(const float* __restrict__ x,
                                               const unsigned short* __restrict__ BT,
                                               unsigned short* __restrict__ Cout) {
  __shared__ unsigned short As[128 * 128];
  const int t = threadIdx.x;
  const int wave = t >> 6, lane = t & 63;
  const int wr = wave >> 1, wc = wave & 1;
  const int l15 = lane & 15, l4 = lane >> 4;
  const int row0 = blockIdx.x * 128;
  {
    const int rr = t >> 4, c8 = t & 15;
#pragma unroll
    for (int c = 0; c < 8; ++c) {
      int row = c * 16 + rr;
      int ar = row0 + row; if (ar >= NN) ar = NN - 1;
      const float* xp = x + (size_t)ar * 128 + c8 * 8;
      v4f f0 = *(const v4f*)(xp);
      v4f f1 = *(const v4f*)(xp + 4);
      u8s u;
      u[0] = f2bf(f0.x); u[1] = f2bf(f0.y); u[2] = f2bf(f0.z); u[3] = f2bf(f0.w);
      u[4] = f2bf(f1.x); u[5] = f2bf(f1.y); u[6] = f2bf(f1.z); u[7] = f2bf(f1.w);
      int sc = c8 ^ (row & 7);
      *(u8s*)&As[row * 128 + sc * 8] = u;
    }
  }
  __syncthreads();
  v4f acc[4][4];
  v4f zero = {0.f, 0.f, 0.f, 0.f};
#pragma unroll
  for (int m = 0; m < 4; ++m)
#pragma unroll
    for (int n = 0; n < 4; ++n) acc[m][n] = zero;
#pragma unroll
  for (int kt = 0; kt < 4; ++kt) {
    v8s a[4], b[4];
#pragma unroll
    for (int m = 0; m < 4; ++m) {
      int row = wr * 64 + m * 16 + l15;
      int j8 = kt * 4 + l4;
      a[m] = *(const v8s*)&As[row * 128 + ((j8 ^ (row & 7)) * 8)];
    }
#pragma unroll
    for (int n = 0; n < 4; ++n)
      b[n] = *(const v8s*)&BT[(size_t)(wc * 64 + n * 16 + l15) * 128 + kt * 32 + l4 * 8];
#pragma unroll
    for (int m = 0; m < 4; ++m)
#pragma unroll
      for (int n = 0; n < 4; ++n)
        acc[m][n] = __builtin_amdgcn_mfma_f32_16x16x32_bf16(a[m], b[n], acc[m][n], 0, 0, 0);
  }
#pragma unroll
  for (int m = 0; m < 4; ++m) {
#pragma unroll
    for (int r = 0; r < 4; ++r) {
      int row = row0 + wr * 64 + m * 16 + l4 * 4 + r;
      if (row < NN) {
#pragma unroll
        for (int n = 0; n < 4; ++n)
          Cout[(size_t)row * 128 + wc * 64 + n * 16 + l15] = f2bf(acc[m][n][r]);
      }
    }
  }
}

// ---------------- CSR gather (SpMM) + fused H0 pack -> fragment-major A2f ----------------
__global__ __launch_bounds__(256) void k_gather(const unsigned short* __restrict__ xwb,
                                                const int2* __restrict__ epack,
                                                const int* __restrict__ rowptr, const int* __restrict__ cnt,
                                                const float* __restrict__ dinv, const float* __restrict__ b1,
                                                const float* __restrict__ H0,
                                                unsigned short* __restrict__ A2f) {
  const int wave = threadIdx.x >> 6, lane = threadIdx.x & 63;
  const int n = blockIdx.x * 4 + wave;  // NN divisible by 4
  const int c0 = lane * 2;
  const int base = __builtin_amdgcn_readfirstlane(rowptr[n]);
  const int len = __builtin_amdgcn_readfirstlane(cnt[n]);
  float di = dinv[n];
  float slf = di * di;
  ushort2 xv = *(const ushort2*)(xwb + (size_t)n * 128 + c0);
  float a0 = b1[c0] + slf * bf2f(xv.x);
  float a1 = b1[c0 + 1] + slf * bf2f(xv.y);
  float p0 = 0.f, p1 = 0.f, q0 = 0.f, q1 = 0.f, r0 = 0.f, r1 = 0.f;
  int j = 0;
  for (; j + 4 <= len; j += 4) {
    int2 m0 = epack[base + j];
    int2 m1 = epack[base + j + 1];
    int2 m2 = epack[base + j + 2];
    int2 m3 = epack[base + j + 3];
    ushort2 v0 = *(const ushort2*)(xwb + (size_t)m0.x * 128 + c0);
    ushort2 v1 = *(const ushort2*)(xwb + (size_t)m1.x * 128 + c0);
    ushort2 v2 = *(const ushort2*)(xwb + (size_t)m2.x * 128 + c0);
    ushort2 v3 = *(const ushort2*)(xwb + (size_t)m3.x * 128 + c0);
    float cf0 = __int_as_float(m0.y), cf1 = __int_as_float(m1.y);
    float cf2 = __int_as_float(m2.y), cf3 = __int_as_float(m3.y);
    a0 += cf0 * bf2f(v0.x); a1 += cf0 * bf2f(v0.y);
    p0 += cf1 * bf2f(v1.x); p1 += cf1 * bf2f(v1.y);
    q0 += cf2 * bf2f(v2.x); q1 += cf2 * bf2f(v2.y);
    r0 += cf3 * bf2f(v3.x); r1 += cf3 * bf2f(v3.y);
  }
  for (; j < len; ++j) {
    int2 m0 = epack[base + j];
    ushort2 v0 = *(const ushort2*)(xwb + (size_t)m0.x * 128 + c0);
    float cf0 = __int_as_float(m0.y);
    a0 += cf0 * bf2f(v0.x);
    a1 += cf0 * bf2f(v0.y);
  }
  a0 += (p0 + q0) + r0;
  a1 += (p1 + q1) + r1;
  // write h[n][c0..c0+1] into fragment-major A2f
  const size_t rbase = ((size_t)(n >> 4) * 12) * 512;
  const int rr8 = (n & 15) * 8;
  {
    int ks = c0 >> 5, kk = c0 & 31, g = kk >> 3, e = kk & 7;
    ushort2 o; o.x = f2bf(a0); o.y = f2bf(a1);
    *(ushort2*)(A2f + rbase + (size_t)ks * 512 + g * 128 + rr8 + e) = o;
  }
  // fused: H0[n][lane*4 .. +3] -> cols 128+lane*4
  {
    int c = 128 + lane * 4;
    v4f hv = *(const v4f*)(H0 + (size_t)n * 256 + lane * 4);
    ushort4 ho; ho.x = f2bf(hv.x); ho.y = f2bf(hv.y); ho.z = f2bf(hv.z); ho.w = f2bf(hv.w);
    int ks = c >> 5, kk = c & 31, g = kk >> 3, e = kk & 7;
    *(ushort4*)(A2f + rbase + (size_t)ks * 512 + g * 128 + rr8 + e) = ho;
  }
}

// ---------------- gates GEMM + fused LSTM epilogue ----------------
// A-panel hoisted to registers ONCE per block (48 x v8s = 192 VGPR), then y-loop over
// all 8 column tiles: B reloaded per y from L2-resident Bf via 4-buffer 3-deep rolling
// prefetch; C0 prefetched under the MFMA burst. No LDS, no barriers; 1 wave/SIMD by design.
__global__ __launch_bounds__(256, 1) void k_gates(const unsigned short* __restrict__ A2f,
                                                  const unsigned short* __restrict__ Bf,
                                                  const float* __restrict__ biasP, const float* __restrict__ C0,
                                                  float* __restrict__ Hn, float* __restrict__ Cn,
                                                  unsigned short* __restrict__ hrelu) {
  const int xb = blockIdx.x;  // 0..781
  const int t = threadIdx.x;
  const int wave = t >> 6, lane = t & 63;
  const int wr = wave >> 1, wc = wave & 1;
  const int l15 = lane & 15, l4 = lane >> 4;
  const int row0 = xb * 128;

  // ---- hoist the whole A-panel slice for this wave: rows wr*64 + m*16, ks=0..11 ----
  v8s av[12][4];
  {
    const unsigned short* ap[4];
#pragma unroll
    for (int m = 0; m < 4; ++m) {
      int rb = xb * 8 + wr * 4 + m;
      if (rb > RBMAX) rb = RBMAX;  // clamped rows computed but never stored
      ap[m] = A2f + (size_t)rb * 12 * 512 + lane * 8;
    }
#pragma unroll
    for (int ks = 0; ks < 12; ++ks)
#pragma unroll
      for (int m = 0; m < 4; ++m)
        av[ks][m] = *(const v8s*)(ap[m] + ks * 512);
  }

  const int gh = 2 * wc + (l15 >> 3);  // hrelu fragment g
  const int eh = l15 & 7;

#pragma unroll 1
  for (int y = 0; y < 8; ++y) {
    const unsigned short* bp[4];
#pragma unroll
    for (int n = 0; n < 4; ++n) {
      int cbi = y * 8 + wc * 4 + n;
      bp[n] = Bf + (size_t)cbi * 12 * 512 + lane * 8;
    }
    // rolling 4-buffer B prefetch, depth 3
    v8s bb[4][4];
#pragma unroll
    for (int k = 0; k < 3; ++k)
#pragma unroll
      for (int n = 0; n < 4; ++n)
        bb[k][n] = *(const v8s*)(bp[n] + k * 512);
    // prefetch C0 for this y (consumed in epilogue; hidden under MFMA burst)
    const int s = (2 * y + wc) * 16 + l15;
    float c0v[4][4];
#pragma unroll
    for (int m = 0; m < 4; ++m)
#pragma unroll
      for (int r = 0; r < 4; ++r) {
        int row = row0 + wr * 64 + m * 16 + l4 * 4 + r;
        if (row >= NN) row = NN - 1;
        c0v[m][r] = C0[(size_t)row * SS + s];
      }

    v4f acc[4][4];
    v4f zero = {0.f, 0.f, 0.f, 0.f};
#pragma unroll
    for (int m = 0; m < 4; ++m)
#pragma unroll
      for (int n = 0; n < 4; ++n) acc[m][n] = zero;

#pragma unroll
    for (int ki = 0; ki < 12; ++ki) {
      if (ki < 9) {
#pragma unroll
        for (int n = 0; n < 4; ++n)
          bb[(ki + 3) & 3][n] = *(const v8s*)(bp[n] + (ki + 3) * 512);
      }
#pragma unroll
      for (int m = 0; m < 4; ++m)
#pragma unroll
        for (int n = 0; n < 4; ++n)
          acc[m][n] = __builtin_amdgcn_mfma_f32_16x16x32_bf16(av[ki][m], bb[ki & 3][n], acc[m][n], 0, 0, 0);
    }

    // epilogue: n-frag index == gate (0:i 1:f 2:c 3:o)
    const int cb = y * 128 + wc * 64 + l15;
    float bi = biasP[cb], bfv = biasP[cb + 16], bcv = biasP[cb + 32], bov = biasP[cb + 48];
#pragma unroll
    for (int m = 0; m < 4; ++m) {
#pragma unroll
      for (int r = 0; r < 4; ++r) {
        int row = row0 + wr * 64 + m * 16 + l4 * 4 + r;
        if (row < NN) {
          float I  = sigmoidf_(acc[m][0][r] + bi);
          float Fg = sigmoidf_(acc[m][1][r] + bfv);
          float T  = tanhf_(acc[m][2][r] + bcv);
          float O  = sigmoidf_(acc[m][3][r] + bov);
          size_t idx = (size_t)row * SS + s;
          float cn = Fg * c0v[m][r] + I * T;
          float hn = O * tanhf_(cn);
          Cn[idx] = cn;
          Hn[idx] = hn;
          hrelu[(((size_t)(row >> 4) * 8 + y) * 512) + gh * 128 + (row & 15) * 8 + eh] =
              f2bf(hn > 0.f ? hn : 0.f);
        }
      }
    }
  }
}

// ---------------- output linear + fused softmax (fragment-major, no LDS/barrier) ----------------
__global__ __launch_bounds__(256) void k_linsoft(const unsigned short* __restrict__ Hf,
                                                 const unsigned short* __restrict__ Wlf,
                                                 const float* __restrict__ bl, float* __restrict__ out) {
  const int t = threadIdx.x;
  const int wave = t >> 6, lane = t & 63;
  const int l15 = lane & 15, l4 = lane >> 4;
  const int row0 = blockIdx.x * 128;
  const int rb0 = (row0 >> 4) + wave * 2;
  v4f acc[2][2];
  v4f zero = {0.f, 0.f, 0.f, 0.f};
#pragma unroll
  for (int m = 0; m < 2; ++m)
#pragma unroll
    for (int n = 0; n < 2; ++n) acc[m][n] = zero;
#pragma unroll
  for (int ks = 0; ks < 8; ++ks) {
    v8s a[2], b[2];
#pragma unroll
    for (int m = 0; m < 2; ++m) {
      int rb = rb0 + m; if (rb > RBMAX) rb = RBMAX;
      a[m] = *(const v8s*)(Hf + ((size_t)rb * 8 + ks) * 512 + lane * 8);
    }
#pragma unroll
    for (int n = 0; n < 2; ++n)
      b[n] = *(const v8s*)(Wlf + ((size_t)n * 8 + ks) * 512 + lane * 8);
#pragma unroll
    for (int m = 0; m < 2; ++m)
#pragma unroll
      for (int n = 0; n < 2; ++n)
        acc[m][n] = __builtin_amdgcn_mfma_f32_16x16x32_bf16(a[m], b[n], acc[m][n], 0, 0, 0);
  }
  float b0 = bl[l15], b1v = bl[16 + l15];
#pragma unroll
  for (int m = 0; m < 2; ++m) {
#pragma unroll
    for (int r = 0; r < 4; ++r) {
      int row = row0 + wave * 32 + m * 16 + l4 * 4 + r;
      float v0 = acc[m][0][r] + b0;
      float v1 = acc[m][1][r] + b1v;
      float mx = fmaxf(v0, v1);
#pragma unroll
      for (int d = 1; d < 16; d <<= 1) mx = fmaxf(mx, __shfl_xor(mx, d, 64));
      float e0 = __expf(v0 - mx), e1 = __expf(v1 - mx);
      float sm = e0 + e1;
#pragma unroll
      for (int d = 1; d < 16; d <<= 1) sm += __shfl_xor(sm, d, 64);
      if (row < NN) {
        out[(size_t)row * 32 + l15] = e0 / sm;
        out[(size_t)row * 32 + 16 + l15] = e1 / sm;
      }
    }
  }
}

extern "C" void kernel_launch(void* const* d_in, const int* in_sizes, int n_in,
                              void* d_out, int out_size, void* d_ws, size_t ws_size,
                              hipStream_t stream) {
  (void)in_sizes; (void)n_in; (void)out_size; (void)ws_size;
  const float* x   = (const float*)d_in[0];
  const int*   ei  = (const int*)d_in[1];
  const float* ew  = (const float*)d_in[2];
  const float* H0  = (const float*)d_in[3];
  const float* C0  = (const float*)d_in[4];
  const float* W1  = (const float*)d_in[5];
  const float* b1  = (const float*)d_in[6];
  const float* Wi  = (const float*)d_in[7];
  const float* Ti  = (const float*)d_in[8];
  const float* bci = (const float*)d_in[9];
  const float* bii = (const float*)d_in[10];
  const float* Wf  = (const float*)d_in[11];
  const float* Tf  = (const float*)d_in[12];
  const float* bcf = (const float*)d_in[13];
  const float* bif = (const float*)d_in[14];
  const float* Wc  = (const float*)d_in[15];
  const float* Tc  = (const float*)d_in[16];
  const float* bcc = (const float*)d_in[17];
  const float* bic = (const float*)d_in[18];
  const float* Wo  = (const float*)d_in[19];
  const float* To  = (const float*)d_in[20];
  const float* bco = (const float*)d_in[21];
  const float* bio = (const float*)d_in[22];
  const float* Wl  = (const float*)d_in[23];
  const float* bl  = (const float*)d_in[24];

  const int* srcI = ei;
  const int* dstI = ei + EE;

  char* ws = (char*)d_ws;
  size_t off = 0;
  auto carve = [&](size_t bytes) -> char* {
    char* p = ws + off;
    off += (bytes + 255) & ~(size_t)255;
    return p;
  };
  float* dinv          = (float*)carve((size_t)NN * 4);
  int*   cnt           = (int*)carve((size_t)NN * 4);
  int*   loc           = (int*)carve((size_t)NN * 4);
  int*   blkSum        = (int*)carve(512 * 4);
  int*   blkOff        = (int*)carve(512 * 4);
  int*   rowptr        = (int*)carve((size_t)NN * 4);
  int*   cursor        = (int*)carve((size_t)NN * 4);
  int2*  epack         = (int2*)carve((size_t)EE * 8);
  unsigned short* W1T  = (unsigned short*)carve((size_t)FF * FF * 2);
  unsigned short* xwb  = (unsigned short*)carve((size_t)NN * FF * 2);
  unsigned short* A2f  = (unsigned short*)carve((size_t)6250 * 12 * 512 * 2);
  unsigned short* Bf   = (unsigned short*)carve((size_t)64 * 12 * 512 * 2);
  float* biasP         = (float*)carve((size_t)NCOL * 4);
  unsigned short* Wlf  = (unsigned short*)carve((size_t)2 * 8 * 512 * 2);
  unsigned short* hrelu = (unsigned short*)carve((size_t)6250 * 8 * 512 * 2);

  float* outSm = (float*)d_out;
  float* HnO = outSm + (size_t)NN * CC;
  float* CnO = HnO + (size_t)NN * SS;

  const int NB = (NN + 255) / 256;  // 391

  k_deg_init<<<NB, 256, 0, stream>>>(dinv, cnt);
  k_deg_acc<<<6250, 256, 0, stream>>>(dstI, ew, dinv, cnt);
  // CSR build (k_scan1 also finalizes dinv)
  k_scan1<<<NB, 256, 0, stream>>>(cnt, loc, blkSum, dinv);
  k_scan2<<<1, 512, 0, stream>>>(blkSum, blkOff, NB);
  k_scan3<<<NB, 256, 0, stream>>>(loc, blkOff, rowptr, cursor);
  k_fill<<<6250, 256, 0, stream>>>(srcI, dstI, ew, dinv, cursor, epack);
  // dense path
  k_pack_w1t<<<64, 256, 0, stream>>>(W1, W1T);
  k_gemm1<<<782, 256, 0, stream>>>(x, W1T, xwb);
  k_gather<<<25000, 256, 0, stream>>>(xwb, epack, rowptr, cnt, dinv, b1, H0, A2f);
  k_pack_bfrag<<<1536, 256, 0, stream>>>(Wi, Wf, Wc, Wo, Ti, Tf, Tc, To, Bf);
  k_pack_bias<<<4, 256, 0, stream>>>(bci, bcf, bcc, bco, bii, bif, bic, bio, biasP);
  k_pack_wlf<<<32, 256, 0, stream>>>(Wl, Wlf);
  k_gates<<<782, 256, 0, stream>>>(A2f, Bf, biasP, C0, HnO, CnO, hrelu);
  k_linsoft<<<782, 256, 0, stream>>>(hrelu, Wlf, bl, outSm);
}

// Round 8
// 611.956 us; speedup vs baseline: 1.5418x; 1.5418x over previous
//
#include <hip/hip_runtime.h>

#define NN 100000
#define EE 1600000
#define FF 128
#define SS 256
#define CC 32
#define KG 384     // gates GEMM K = F + S
#define NCOL 1024  // gates GEMM N = 4 gates * S

typedef __attribute__((ext_vector_type(8))) short v8s;
typedef __attribute__((ext_vector_type(8))) unsigned short u8s;
typedef __attribute__((ext_vector_type(4))) float v4f;

__device__ __forceinline__ void gload_lds16(const void* g, void* l) {
  __builtin_amdgcn_global_load_lds(
      (const __attribute__((address_space(1))) void*)g,
      (__attribute__((address_space(3))) void*)l, 16, 0, 0);
}

__device__ __forceinline__ unsigned short f2bf(float f) {
  unsigned int u = __float_as_uint(f);
  u += 0x7FFF + ((u >> 16) & 1);  // RNE
  return (unsigned short)(u >> 16);
}
__device__ __forceinline__ float bf2f(unsigned short u) {
  return __uint_as_float(((unsigned int)u) << 16);
}
__device__ __forceinline__ float sigmoidf_(float x) { return 1.0f / (1.0f + __expf(-x)); }
__device__ __forceinline__ float tanhf_(float x) {
  float ax = fabsf(x);
  float e = __expf(2.0f * ax);
  float t = 1.0f - 2.0f / (e + 1.0f);
  return copysignf(t, x);
}

// ---------------- degree / norm + edge histogram ----------------
__global__ __launch_bounds__(256) void k_deg_init(float* deg, int* cnt) {
  int i = blockIdx.x * 256 + threadIdx.x;
  if (i < NN) { deg[i] = 1.0f; cnt[i] = 0; }
}
__global__ __launch_bounds__(256) void k_deg_acc(const int* __restrict__ dst,
                                                 const float* __restrict__ w,
                                                 float* __restrict__ deg,
                                                 int* __restrict__ cnt) {
  int e = blockIdx.x * 256 + threadIdx.x;
  if (e < EE) {
    int d = dst[e];
    unsafeAtomicAdd(&deg[d], w[e]);
    atomicAdd(&cnt[d], 1);
  }
}

// ---------------- CSR build: scan (fused dinv) + fill ----------------
__global__ __launch_bounds__(256) void k_scan1(const int* __restrict__ cnt, int* __restrict__ loc,
                                               int* __restrict__ blkSum, float* __restrict__ deg) {
  __shared__ int s[256];
  int i = blockIdx.x * 256 + threadIdx.x;
  if (i < NN) { float d = deg[i]; deg[i] = d > 0.f ? rsqrtf(d) : 0.f; }  // fused dinv
  int v = (i < NN) ? cnt[i] : 0;
  s[threadIdx.x] = v;
  __syncthreads();
#pragma unroll
  for (int d = 1; d < 256; d <<= 1) {
    int t = (threadIdx.x >= d) ? s[threadIdx.x - d] : 0;
    __syncthreads();
    s[threadIdx.x] += t;
    __syncthreads();
  }
  if (i < NN) loc[i] = s[threadIdx.x] - v;  // exclusive
  if (threadIdx.x == 255) blkSum[blockIdx.x] = s[255];
}
__global__ __launch_bounds__(512) void k_scan2(int* __restrict__ blkSum, int* __restrict__ blkOff, int nb) {
  __shared__ int s[512];
  int v = (threadIdx.x < nb) ? blkSum[threadIdx.x] : 0;
  s[threadIdx.x] = v;
  __syncthreads();
#pragma unroll
  for (int d = 1; d < 512; d <<= 1) {
    int t = (threadIdx.x >= d) ? s[threadIdx.x - d] : 0;
    __syncthreads();
    s[threadIdx.x] += t;
    __syncthreads();
  }
  if (threadIdx.x < nb) blkOff[threadIdx.x] = s[threadIdx.x] - v;  // exclusive
}
__global__ __launch_bounds__(256) void k_scan3(const int* __restrict__ loc, const int* __restrict__ blkOff,
                                               int* __restrict__ rowptr, int* __restrict__ cursor) {
  int i = blockIdx.x * 256 + threadIdx.x;
  if (i < NN) {
    int v = loc[i] + blkOff[blockIdx.x];
    rowptr[i] = v;
    cursor[i] = v;
  }
}
__global__ __launch_bounds__(256) void k_fill(const int* __restrict__ src, const int* __restrict__ dst,
                                              const float* __restrict__ w, const float* __restrict__ dinv,
                                              int* __restrict__ cursor, int2* __restrict__ epack) {
  int e = blockIdx.x * 256 + threadIdx.x;
  if (e >= EE) return;
  int s = src[e], d = dst[e];
  int pos = atomicAdd(&cursor[d], 1);
  float coef = dinv[s] * w[e] * dinv[d];
  int2 m; m.x = s; m.y = __float_as_int(coef);
  epack[pos] = m;
}

// ---------------- packs ----------------
__global__ __launch_bounds__(256) void k_pack_w1t(const float* __restrict__ W1, unsigned short* __restrict__ W1T) {
  int i = blockIdx.x * 256 + threadIdx.x;  // 128*128
  if (i < FF * FF) {
    int col = i >> 7, k = i & 127;
    W1T[i] = f2bf(W1[k * FF + col]);
  }
}
// B^T plane-major: BTk[p][col][8], p=k/8, col = (s&15) + 16*g + 64*(s>>4)
__global__ __launch_bounds__(256) void k_pack_btk(const float* __restrict__ Wi, const float* __restrict__ Wf,
                                                  const float* __restrict__ Wc, const float* __restrict__ Wo,
                                                  const float* __restrict__ Ti, const float* __restrict__ Tf,
                                                  const float* __restrict__ Tc, const float* __restrict__ To,
                                                  unsigned short* __restrict__ BTk) {
  int i = blockIdx.x * 256 + threadIdx.x;  // 1024*384
  if (i >= NCOL * KG) return;
  int col = i / KG, k = i - col * KG;
  int th = col >> 6, rem = col & 63, g = rem >> 4, slo = rem & 15;
  int s = th * 16 + slo;
  const float* Wp = (g == 0) ? Wi : (g == 1) ? Wf : (g == 2) ? Wc : Wo;
  const float* Tp = (g == 0) ? Ti : (g == 1) ? Tf : (g == 2) ? Tc : To;
  float v = (k < FF) ? Wp[(size_t)k * SS + s] : Tp[(size_t)(k - FF) * SS + s];
  int p = k >> 3, j = k & 7;
  BTk[((size_t)p * NCOL + col) * 8 + j] = f2bf(v);
}
__global__ __launch_bounds__(256) void k_pack_bias(const float* bci, const float* bcf, const float* bcc, const float* bco,
                                                   const float* bi, const float* bf, const float* bc_, const float* bo,
                                                   float* biasP) {
  int col = blockIdx.x * 256 + threadIdx.x;
  if (col >= NCOL) return;
  int th = col >> 6, rem = col & 63, g = rem >> 4, slo = rem & 15;
  int s = th * 16 + slo;
  const float* P = (g == 0) ? bci : (g == 1) ? bcf : (g == 2) ? bcc : bco;
  const float* Q = (g == 0) ? bi : (g == 1) ? bf : (g == 2) ? bc_ : bo;
  biasP[col] = P[s] + Q[s];
}
__global__ __launch_bounds__(256) void k_pack_wlt(const float* __restrict__ Wl, unsigned short* __restrict__ WlT) {
  int i = blockIdx.x * 256 + threadIdx.x;  // 32*256
  if (i >= CC * SS) return;
  int c = i >> 8, k = i & 255;
  WlT[i] = f2bf(Wl[(size_t)k * CC + c]);
}

// ---------------- GEMM1: xw = f2bf(x) @ W1, fused fp32->bf16 pack ----------------
__global__ __launch_bounds__(256) void k_gemm1(const float* __restrict__ x,
                                               const unsigned short* __restrict__ BT,
                                               unsigned short* __restrict__ Cout) {
  __shared__ unsigned short As[128 * 128];
  const int t = threadIdx.x;
  const int wave = t >> 6, lane = t & 63;
  const int wr = wave >> 1, wc = wave & 1;
  const int l15 = lane & 15, l4 = lane >> 4;
  const int row0 = blockIdx.x * 128;
  {
    const int rr = t >> 4, c8 = t & 15;
#pragma unroll
    for (int c = 0; c < 8; ++c) {
      int row = c * 16 + rr;
      int ar = row0 + row; if (ar >= NN) ar = NN - 1;
      const float* xp = x + (size_t)ar * 128 + c8 * 8;
      v4f f0 = *(const v4f*)(xp);
      v4f f1 = *(const v4f*)(xp + 4);
      u8s u;
      u[0] = f2bf(f0.x); u[1] = f2bf(f0.y); u[2] = f2bf(f0.z); u[3] = f2bf(f0.w);
      u[4] = f2bf(f1.x); u[5] = f2bf(f1.y); u[6] = f2bf(f1.z); u[7] = f2bf(f1.w);
      int sc = c8 ^ (row & 7);
      *(u8s*)&As[row * 128 + sc * 8] = u;
    }
  }
  __syncthreads();
  v4f acc[4][4];
  v4f zero = {0.f, 0.f, 0.f, 0.f};
#pragma unroll
  for (int m = 0; m < 4; ++m)
#pragma unroll
    for (int n = 0; n < 4; ++n) acc[m][n] = zero;
#pragma unroll
  for (int kt = 0; kt < 4; ++kt) {
    v8s a[4], b[4];
#pragma unroll
    for (int m = 0; m < 4; ++m) {
      int row = wr * 64 + m * 16 + l15;
      int j8 = kt * 4 + l4;
      a[m] = *(const v8s*)&As[row * 128 + ((j8 ^ (row & 7)) * 8)];
    }
#pragma unroll
    for (int n = 0; n < 4; ++n)
      b[n] = *(const v8s*)&BT[(size_t)(wc * 64 + n * 16 + l15) * 128 + kt * 32 + l4 * 8];
#pragma unroll
    for (int m = 0; m < 4; ++m)
#pragma unroll
      for (int n = 0; n < 4; ++n)
        acc[m][n] = __builtin_amdgcn_mfma_f32_16x16x32_bf16(a[m], b[n], acc[m][n], 0, 0, 0);
  }
#pragma unroll
  for (int m = 0; m < 4; ++m) {
#pragma unroll
    for (int r = 0; r < 4; ++r) {
      int row = row0 + wr * 64 + m * 16 + l4 * 4 + r;
      if (row < NN) {
#pragma unroll
        for (int n = 0; n < 4; ++n)
          Cout[(size_t)row * 128 + wc * 64 + n * 16 + l15] = f2bf(acc[m][n][r]);
      }
    }
  }
}

// ---------------- CSR gather (SpMM) + fused H0 pack: 2 edges/wave, 8B loads ----------------
__global__ __launch_bounds__(256) void k_gather(const unsigned short* __restrict__ xwb,
                                                const int2* __restrict__ epack,
                                                const int* __restrict__ rowptr, const int* __restrict__ cnt,
                                                const float* __restrict__ dinv, const float* __restrict__ b1,
                                                const float* __restrict__ H0,
                                                unsigned short* __restrict__ A2) {
  const int wave = threadIdx.x >> 6, lane = threadIdx.x & 63;
  const int n = blockIdx.x * 4 + wave;  // NN divisible by 4
  const int half = lane >> 5, l32 = lane & 31;
  const int c0 = l32 * 4;               // 4 cols per lane, 32 lanes cover the row
  const int base = __builtin_amdgcn_readfirstlane(rowptr[n]);
  const int len = __builtin_amdgcn_readfirstlane(cnt[n]);
  float a0 = 0.f, a1 = 0.f, a2 = 0.f, a3 = 0.f;
  if (half == 0) {
    float di = dinv[n];
    float slf = di * di;
    ushort4 xv = *(const ushort4*)(xwb + (size_t)n * 128 + c0);
    a0 = b1[c0]     + slf * bf2f(xv.x);
    a1 = b1[c0 + 1] + slf * bf2f(xv.y);
    a2 = b1[c0 + 2] + slf * bf2f(xv.z);
    a3 = b1[c0 + 3] + slf * bf2f(xv.w);
  }
  float p0 = 0.f, p1 = 0.f, p2 = 0.f, p3 = 0.f;
  const int pairs = len >> 1;
  int j = 0;
  for (; j + 2 <= pairs; j += 2) {   // 4 edges per iteration (2 per half-wave)
    int2 m0 = epack[base + 2 * j + half];
    int2 m1 = epack[base + 2 * j + 2 + half];
    ushort4 v0 = *(const ushort4*)(xwb + (size_t)m0.x * 128 + c0);
    ushort4 v1 = *(const ushort4*)(xwb + (size_t)m1.x * 128 + c0);
    float cf0 = __int_as_float(m0.y), cf1 = __int_as_float(m1.y);
    a0 += cf0 * bf2f(v0.x); a1 += cf0 * bf2f(v0.y);
    a2 += cf0 * bf2f(v0.z); a3 += cf0 * bf2f(v0.w);
    p0 += cf1 * bf2f(v1.x); p1 += cf1 * bf2f(v1.y);
    p2 += cf1 * bf2f(v1.z); p3 += cf1 * bf2f(v1.w);
  }
  if (j < pairs) {
    int2 m0 = epack[base + 2 * j + half];
    ushort4 v0 = *(const ushort4*)(xwb + (size_t)m0.x * 128 + c0);
    float cf0 = __int_as_float(m0.y);
    a0 += cf0 * bf2f(v0.x); a1 += cf0 * bf2f(v0.y);
    a2 += cf0 * bf2f(v0.z); a3 += cf0 * bf2f(v0.w);
  }
  if ((len & 1) && half == 0) {      // odd tail edge
    int2 m0 = epack[base + len - 1];
    ushort4 v0 = *(const ushort4*)(xwb + (size_t)m0.x * 128 + c0);
    float cf0 = __int_as_float(m0.y);
    a0 += cf0 * bf2f(v0.x); a1 += cf0 * bf2f(v0.y);
    a2 += cf0 * bf2f(v0.z); a3 += cf0 * bf2f(v0.w);
  }
  a0 += p0; a1 += p1; a2 += p2; a3 += p3;
  a0 += __shfl_xor(a0, 32, 64);
  a1 += __shfl_xor(a1, 32, 64);
  a2 += __shfl_xor(a2, 32, 64);
  a3 += __shfl_xor(a3, 32, 64);
  if (half == 0) {
    ushort4 o; o.x = f2bf(a0); o.y = f2bf(a1); o.z = f2bf(a2); o.w = f2bf(a3);
    *(ushort4*)(A2 + (size_t)n * KG + c0) = o;
  }
  // fused: H0 f32 -> bf16 into A2 cols [128,384)
  v4f hv = *(const v4f*)(H0 + (size_t)n * 256 + lane * 4);
  ushort4 ho; ho.x = f2bf(hv.x); ho.y = f2bf(hv.y); ho.z = f2bf(hv.z); ho.w = f2bf(hv.w);
  *(ushort4*)(A2 + (size_t)n * KG + 128 + lane * 4) = ho;
}

// ---------------- gates GEMM + fused LSTM epilogue ----------------
// A: 3-buffer LDS, 2-deep stage prefetch. B: explicit register double-buffer (bbA/bbB),
// loaded one kk-step ahead from L2-resident plane-major BTk -> MFMA clusters run on
// register-resident operands. Raw s_barrier, single prologue vmcnt. XCD-chunked mapping.
__global__ __launch_bounds__(256, 3) void k_gates(const unsigned short* __restrict__ A2,
                                                  const unsigned short* __restrict__ BTk,
                                                  const float* __restrict__ biasP, const float* __restrict__ C0,
                                                  float* __restrict__ Hn, float* __restrict__ Cn,
                                                  unsigned short* __restrict__ hrelu) {
  __shared__ unsigned short As[3][128 * 64];
  const int g = blockIdx.x;
  const int xcd = g & 7, li = g >> 3;
  const int xl = li >> 3, y = li & 7;   // per-XCD: y fastest -> A-panel L2 reuse
  const int xb = xcd * 98 + xl;
  if (xb >= 782) return;
  const int t = threadIdx.x;
  const int wave = t >> 6, lane = t & 63;
  const int wr = wave >> 1, wc = wave & 1;
  const int l15 = lane & 15, l4 = lane >> 4;
  const int row0 = xb * 128, crow0 = y * 128;
  const int r_in = t >> 3, chunk = t & 7;

#define STAGE(buf, kt)                                                          \
  {                                                                             \
    _Pragma("unroll") for (int c = 0; c < 4; ++c) {                             \
      int row = c * 32 + r_in;                                                  \
      int ar = row0 + row; if (ar >= NN) ar = NN - 1;                           \
      int sc = chunk ^ (row & 7);                                               \
      gload_lds16(A2 + (size_t)ar * KG + (kt) * 64 + sc * 8,                    \
                  &As[buf][row * 64 + chunk * 8]);                              \
    }                                                                           \
  }

  const unsigned short* Bb[4];
#pragma unroll
  for (int n = 0; n < 4; ++n)
    Bb[n] = BTk + ((size_t)l4 * NCOL + (crow0 + wc * 64 + n * 16 + l15)) * 8;
  // step s (=kt*2+kk, 0..11) lives at planes 4s..4s+3 -> offset s*4*NCOL*8 ushorts
#define LOADB(dst, s)                                                           \
  {                                                                             \
    _Pragma("unroll") for (int n = 0; n < 4; ++n)                               \
      dst[n] = *(const v8s*)(Bb[n] + (size_t)(s) * 4 * NCOL * 8);               \
  }

  v4f acc[4][4];
  v4f zero = {0.f, 0.f, 0.f, 0.f};
#pragma unroll
  for (int m = 0; m < 4; ++m)
#pragma unroll
    for (int n = 0; n < 4; ++n) acc[m][n] = zero;

  v8s bbA[4], bbB[4];
  LOADB(bbA, 0);
  STAGE(0, 0);
  STAGE(1, 1);
  asm volatile("s_waitcnt vmcnt(4)" ::: "memory");  // bbA + stage0 done; stage1 in flight
  __builtin_amdgcn_sched_barrier(0);
  asm volatile("s_barrier" ::: "memory");

#pragma unroll
  for (int kt = 0; kt < 6; ++kt) {
    const int cur = kt % 3;
    LOADB(bbB, 2 * kt + 1);                 // next kk's B, covered by kk0 MFMAs
    if (kt < 4) STAGE((kt + 2) % 3, kt + 2);
    {  // kk0: register-resident bbA
      v8s a[4];
#pragma unroll
      for (int m = 0; m < 4; ++m) {
        int row = wr * 64 + m * 16 + l15;
        a[m] = *(const v8s*)&As[cur][row * 64 + ((l4 ^ (row & 7)) * 8)];
      }
#pragma unroll
      for (int m = 0; m < 4; ++m)
#pragma unroll
        for (int n = 0; n < 4; ++n)
          acc[m][n] = __builtin_amdgcn_mfma_f32_16x16x32_bf16(a[m], bbA[n], acc[m][n], 0, 0, 0);
    }
    if (kt < 5) LOADB(bbA, 2 * kt + 2);     // next phase's first B, covered by kk1 MFMAs
    {  // kk1: register-resident bbB
      v8s a[4];
#pragma unroll
      for (int m = 0; m < 4; ++m) {
        int row = wr * 64 + m * 16 + l15;
        a[m] = *(const v8s*)&As[cur][row * 64 + (((4 + l4) ^ (row & 7)) * 8)];
      }
#pragma unroll
      for (int m = 0; m < 4; ++m)
#pragma unroll
        for (int n = 0; n < 4; ++n)
          acc[m][n] = __builtin_amdgcn_mfma_f32_16x16x32_bf16(a[m], bbB[n], acc[m][n], 0, 0, 0);
    }
    if (kt < 5) {
      __builtin_amdgcn_sched_barrier(0);
      asm volatile("s_barrier" ::: "memory");
    }
  }
#undef STAGE
#undef LOADB

  // epilogue: n-frag index == gate (0:i 1:f 2:c 3:o), s = (2*y+wc)*16 + l15
  const int s = (2 * y + wc) * 16 + l15;
  const int cb = crow0 + wc * 64 + l15;
  float bi = biasP[cb], bfv = biasP[cb + 16], bcv = biasP[cb + 32], bov = biasP[cb + 48];
#pragma unroll
  for (int m = 0; m < 4; ++m) {
#pragma unroll
    for (int r = 0; r < 4; ++r) {
      int row = row0 + wr * 64 + m * 16 + l4 * 4 + r;
      if (row < NN) {
        float I  = sigmoidf_(acc[m][0][r] + bi);
        float Fg = sigmoidf_(acc[m][1][r] + bfv);
        float T  = tanhf_(acc[m][2][r] + bcv);
        float O  = sigmoidf_(acc[m][3][r] + bov);
        size_t idx = (size_t)row * SS + s;
        float c0 = C0[idx];
        float cn = Fg * c0 + I * T;
        float hn = O * tanhf_(cn);
        Cn[idx] = cn;
        Hn[idx] = hn;
        hrelu[idx] = f2bf(hn > 0.f ? hn : 0.f);
      }
    }
  }
}

// ---------------- output linear + fused softmax ----------------
__global__ __launch_bounds__(256) void k_linsoft(const unsigned short* __restrict__ Arelu,
                                                 const unsigned short* __restrict__ WlT,
                                                 const float* __restrict__ bl, float* __restrict__ out) {
  __shared__ unsigned short As[128 * 256];
  const int t = threadIdx.x;
  const int wave = t >> 6, lane = t & 63;
  const int l15 = lane & 15, l4 = lane >> 4;
  const int row0 = blockIdx.x * 128;
#pragma unroll
  for (int c = 0; c < 16; ++c) {
    int slot = c * 256 + t;
    int row = slot >> 5, chunk = slot & 31;
    int ar = row0 + row; if (ar >= NN) ar = NN - 1;
    int sc = chunk ^ (row & 7);
    gload_lds16(Arelu + (size_t)ar * 256 + sc * 8, &As[row * 256 + chunk * 8]);
  }
  v8s bfr[8][2];
#pragma unroll
  for (int ks = 0; ks < 8; ++ks)
#pragma unroll
    for (int n = 0; n < 2; ++n)
      bfr[ks][n] = *(const v8s*)&WlT[(size_t)(n * 16 + l15) * 256 + ks * 32 + l4 * 8];
  v4f acc[2][2];
  v4f zero = {0.f, 0.f, 0.f, 0.f};
#pragma unroll
  for (int m = 0; m < 2; ++m)
#pragma unroll
    for (int n = 0; n < 2; ++n) acc[m][n] = zero;
  __syncthreads();
#pragma unroll
  for (int ks = 0; ks < 8; ++ks) {
    v8s a[2];
#pragma unroll
    for (int m = 0; m < 2; ++m) {
      int row = wave * 32 + m * 16 + l15;
      int j8 = ks * 4 + l4;
      a[m] = *(const v8s*)&As[row * 256 + ((j8 ^ (row & 7)) * 8)];
    }
#pragma unroll
    for (int m = 0; m < 2; ++m)
#pragma unroll
      for (int n = 0; n < 2; ++n)
        acc[m][n] = __builtin_amdgcn_mfma_f32_16x16x32_bf16(a[m], bfr[ks][n], acc[m][n], 0, 0, 0);
  }
  float b0 = bl[l15], b1v = bl[16 + l15];
#pragma unroll
  for (int m = 0; m < 2; ++m) {
#pragma unroll
    for (int r = 0; r < 4; ++r) {
      int row = row0 + wave * 32 + m * 16 + l4 * 4 + r;
      float v0 = acc[m][0][r] + b0;
      float v1 = acc[m][1][r] + b1v;
      float mx = fmaxf(v0, v1);
#pragma unroll
      for (int d = 1; d < 16; d <<= 1) mx = fmaxf(mx, __shfl_xor(mx, d, 64));
      float e0 = __expf(v0 - mx), e1 = __expf(v1 - mx);
      float sm = e0 + e1;
#pragma unroll
      for (int d = 1; d < 16; d <<= 1) sm += __shfl_xor(sm, d, 64);
      if (row < NN) {
        out[(size_t)row * 32 + l15] = e0 / sm;
        out[(size_t)row * 32 + 16 + l15] = e1 / sm;
      }
    }
  }
}

extern "C" void kernel_launch(void* const* d_in, const int* in_sizes, int n_in,
                              void* d_out, int out_size, void* d_ws, size_t ws_size,
                              hipStream_t stream) {
  (void)in_sizes; (void)n_in; (void)out_size; (void)ws_size;
  const float* x   = (const float*)d_in[0];
  const int*   ei  = (const int*)d_in[1];
  const float* ew  = (const float*)d_in[2];
  const float* H0  = (const float*)d_in[3];
  const float* C0  = (const float*)d_in[4];
  const float* W1  = (const float*)d_in[5];
  const float* b1  = (const float*)d_in[6];
  const float* Wi  = (const float*)d_in[7];
  const float* Ti  = (const float*)d_in[8];
  const float* bci = (const float*)d_in[9];
  const float* bii = (const float*)d_in[10];
  const float* Wf  = (const float*)d_in[11];
  const float* Tf  = (const float*)d_in[12];
  const float* bcf = (const float*)d_in[13];
  const float* bif = (const float*)d_in[14];
  const float* Wc  = (const float*)d_in[15];
  const float* Tc  = (const float*)d_in[16];
  const float* bcc = (const float*)d_in[17];
  const float* bic = (const float*)d_in[18];
  const float* Wo  = (const float*)d_in[19];
  const float* To  = (const float*)d_in[20];
  const float* bco = (const float*)d_in[21];
  const float* bio = (const float*)d_in[22];
  const float* Wl  = (const float*)d_in[23];
  const float* bl  = (const float*)d_in[24];

  const int* srcI = ei;
  const int* dstI = ei + EE;

  char* ws = (char*)d_ws;
  size_t off = 0;
  auto carve = [&](size_t bytes) -> char* {
    char* p = ws + off;
    off += (bytes + 255) & ~(size_t)255;
    return p;
  };
  float* dinv          = (float*)carve((size_t)NN * 4);
  int*   cnt           = (int*)carve((size_t)NN * 4);
  int*   loc           = (int*)carve((size_t)NN * 4);
  int*   blkSum        = (int*)carve(512 * 4);
  int*   blkOff        = (int*)carve(512 * 4);
  int*   rowptr        = (int*)carve((size_t)NN * 4);
  int*   cursor        = (int*)carve((size_t)NN * 4);
  int2*  epack         = (int2*)carve((size_t)EE * 8);
  unsigned short* W1T  = (unsigned short*)carve((size_t)FF * FF * 2);
  unsigned short* xwb  = (unsigned short*)carve((size_t)NN * FF * 2);
  unsigned short* A2   = (unsigned short*)carve((size_t)NN * KG * 2);
  unsigned short* BTk  = (unsigned short*)carve((size_t)NCOL * KG * 2);
  float* biasP         = (float*)carve((size_t)NCOL * 4);
  unsigned short* WlT  = (unsigned short*)carve((size_t)CC * SS * 2);
  unsigned short* hrelu = (unsigned short*)carve((size_t)NN * SS * 2);

  float* outSm = (float*)d_out;
  float* HnO = outSm + (size_t)NN * CC;
  float* CnO = HnO + (size_t)NN * SS;

  const int NB = (NN + 255) / 256;  // 391

  k_deg_init<<<NB, 256, 0, stream>>>(dinv, cnt);
  k_deg_acc<<<6250, 256, 0, stream>>>(dstI, ew, dinv, cnt);
  // CSR build (k_scan1 also finalizes dinv)
  k_scan1<<<NB, 256, 0, stream>>>(cnt, loc, blkSum, dinv);
  k_scan2<<<1, 512, 0, stream>>>(blkSum, blkOff, NB);
  k_scan3<<<NB, 256, 0, stream>>>(loc, blkOff, rowptr, cursor);
  k_fill<<<6250, 256, 0, stream>>>(srcI, dstI, ew, dinv, cursor, epack);
  // dense path
  k_pack_w1t<<<64, 256, 0, stream>>>(W1, W1T);
  k_gemm1<<<782, 256, 0, stream>>>(x, W1T, xwb);
  k_gather<<<25000, 256, 0, stream>>>(xwb, epack, rowptr, cnt, dinv, b1, H0, A2);
  k_pack_btk<<<1536, 256, 0, stream>>>(Wi, Wf, Wc, Wo, Ti, Tf, Tc, To, BTk);
  k_pack_bias<<<4, 256, 0, stream>>>(bci, bcf, bcc, bco, bii, bif, bic, bio, biasP);
  k_pack_wlt<<<32, 256, 0, stream>>>(Wl, WlT);
  k_gates<<<6272, 256, 0, stream>>>(A2, BTk, biasP, C0, HnO, CnO, hrelu);
  k_linsoft<<<782, 256, 0, stream>>>(hrelu, WlT, bl, outSm);
}